// Round 6
// baseline (284.724 us; speedup 1.0000x reference)
//
#include <hip/hip_runtime.h>
#include <hip/hip_bf16.h>

// Problem constants (match reference)
#define NPTS 400000          // == 6250 * 64 exactly
#define NVOX 100000
#define EPSB 1e-3f
#define NTILE 6250
#define NBLK_SCAN 391        // ceil(NVOX/256)
#define GBLK 1563            // k_prep grid (1 pt/thread)

// ws layout (in floats) — ~60 MB
#define OFF_ACC4   0                          // 4*NVOX [cnt,sx,sy,sz]
#define OFF_GRAM   (4*NVOX)                   // 72: sx[10]+sxx[55]
#define OFF_P1     (OFF_GRAM + 128)           // 32 slots * 128
#define ZERO_FLOATS (OFF_P1 + 4096)           // zeroed prefix (~1.6 MB)
#define OFF_V0     ZERO_FLOATS                // NVOX*64 fp32 h0 max (spanning rows zeroed by scan3)
#define OFF_Y1M    (OFF_V0 + NVOX*64)         // NVOX*64 raw y1 max (fkey; spanning rows zeroed)
#define OFF_VTMP   (OFF_Y1M + NVOX*64)        // NVOX
#define OFF_BSUM   (OFF_VTMP + NVOX)          // 512
#define OFF_VOFF   (OFF_BSUM + 512)           // NVOX (scatter cursors)
#define OFF_VSTART (OFF_VOFF + NVOX)          // NVOX+8 (+ sentinel)
#define OFF_VS     (OFF_VSTART + NVOX + 8)    // NPTS (vsorted, sequential fill)
#define OFF_W0F    (OFF_VS + NPTS)            // 640
#define OFF_W1B    (OFF_W0F + 640)            // 4096 floats = 8192 bf16
#define OFF_PFS    (OFF_W1B + 4096)           // NPTS uint4 records {featlo,feathi,v,i}
#define OFF_H0T    (OFF_PFS + 4*NPTS)         // NPTS*64 bf16 = NPTS*32 floats (sorted h0 tiles)

#define XTB_LD 136
#define HT_LD  65

typedef __bf16 bf16x8 __attribute__((ext_vector_type(8)));
typedef float  f32x4  __attribute__((ext_vector_type(4)));

__device__ __forceinline__ float b2f(__hip_bfloat16 h) { return __bfloat162float(h); }
__device__ __forceinline__ float bfbits2f(unsigned short u) {
    return __uint_as_float((unsigned int)u << 16);
}
__device__ __forceinline__ unsigned short bf16u(float f) {
    __hip_bfloat16 h = __float2bfloat16(f);
    return __builtin_bit_cast(unsigned short, h);
}
__device__ __forceinline__ unsigned int fkey(float f) {
    unsigned int u = __float_as_uint(f);
    return (u & 0x80000000u) ? ~u : (u | 0x80000000u);
}
__device__ __forceinline__ float funkey(unsigned int k) {
    unsigned int u = (k & 0x80000000u) ? (k & 0x7FFFFFFFu) : ~k;
    return __uint_as_float(u);
}

// xv from an already-loaded feat quad + voxel stats/coords
__device__ __forceinline__ void compute_x_from(unsigned int flo, unsigned int fhi,
                                               const float* __restrict__ acc4,
                                               const int* __restrict__ coors,
                                               int v, float* xv) {
    float px = bfbits2f((unsigned short)(flo & 0xffffu));
    float py = bfbits2f((unsigned short)(flo >> 16));
    float pz = bfbits2f((unsigned short)(fhi & 0xffffu));
    float it = bfbits2f((unsigned short)(fhi >> 16));
    float4 a4 = *(const float4*)&acc4[4 * (long)v];
    float ic = 1.0f / a4.x;
    int4 c4 = *(const int4*)&coors[4 * (long)v];   // (b, z, y, x)
    xv[0] = px; xv[1] = py; xv[2] = pz;
    xv[3] = px - a4.y * ic; xv[4] = py - a4.z * ic; xv[5] = pz - a4.w * ic;
    xv[6] = px - ((float)c4.w * 0.2f + 0.1f);
    xv[7] = py - ((float)c4.z * 0.2f + 0.1f - 40.0f);
    xv[8] = pz - ((float)c4.y * 4.0f + 2.0f - 3.0f);
    xv[9] = it;
}

// ---- K1: per-voxel count + xyz sums; last block converts weights
// (W0 -> fp32; W1 -> bf16 MFMA B-fragment order). ----
__global__ void k_vsum(const __hip_bfloat16* __restrict__ feat,
                       const int* __restrict__ inv,
                       float* __restrict__ acc4,
                       const __hip_bfloat16* __restrict__ W0,
                       const __hip_bfloat16* __restrict__ W1,
                       float* __restrict__ W0f, unsigned short* __restrict__ w1b) {
    if (blockIdx.x == 6250) {
        int t = threadIdx.x;
        for (int j = t; j < 640; j += 256) W0f[j] = b2f(W0[j]);
        for (int f = t; f < 8192; f += 256) {
            int j  = f & 7;
            int l  = (f >> 3) & 63;
            int ks = (f >> 9) & 3;
            int ct = f >> 11;
            int ch = ct * 16 + (l & 15);
            int k  = ks * 32 + ((l >> 4) & 3) * 8 + j;
            w1b[f] = __builtin_bit_cast(unsigned short, W1[ch * 128 + k]);
        }
        return;
    }
    long t = (long)blockIdx.x * 256 + threadIdx.x;
    int pt = (int)(t >> 2);
    int comp = (int)(t & 3);
    float val = (comp == 0) ? 1.0f : b2f(feat[4 * pt + comp - 1]);
    int v = inv[pt];
    atomicAdd(&acc4[(long)v * 4 + comp], val);
}

// ---- prefix scan of voxel counts ----
__global__ void k_scan1(const float* __restrict__ acc4,
                        int* __restrict__ vtmp, int* __restrict__ bsum) {
    __shared__ int sc[256];
    int b = blockIdx.x, t = threadIdx.x;
    int v = b * 256 + t;
    int c = (v < NVOX) ? (int)acc4[4 * (long)v] : 0;
    sc[t] = c;
    __syncthreads();
    int val = c;
    for (int off = 1; off < 256; off <<= 1) {
        int x = (t >= off) ? sc[t - off] : 0;
        __syncthreads();
        val += x; sc[t] = val;
        __syncthreads();
    }
    if (v < NVOX) vtmp[v] = val - c;
    if (t == 255) bsum[b] = val;
}

__global__ void k_scan2(int* __restrict__ bsum) {
    __shared__ int sc[512];
    int t = threadIdx.x;
    int c = (t < NBLK_SCAN) ? bsum[t] : 0;
    sc[t] = c;
    __syncthreads();
    int val = c;
    for (int off = 1; off < 512; off <<= 1) {
        int x = (t >= off) ? sc[t - off] : 0;
        __syncthreads();
        val += x; sc[t] = val;
        __syncthreads();
    }
    if (t < NBLK_SCAN) bsum[t] = val - c;
}

// ---- scan3: finalize offsets; fill vsorted by sequential per-voxel runs
// (streaming writes, no scatter amplification); zero-init v0/y1m rows ONLY
// for voxels that span an aligned 16-pt window (the atomicMax path). ----
__global__ void k_scan3(const int* __restrict__ vtmp, const int* __restrict__ bsum,
                        int* __restrict__ voff, int* __restrict__ vstart,
                        int* __restrict__ vsorted,
                        float* __restrict__ v0, unsigned int* __restrict__ y1m) {
    int v = blockIdx.x * 256 + threadIdx.x;
    if (v < NVOX) {
        int s0 = vtmp[v] + bsum[v >> 8];
        voff[v] = s0;
        vstart[v] = s0;
        int s1;
        if (v + 1 < NVOX) s1 = vtmp[v + 1] + bsum[(v + 1) >> 8];
        else              s1 = NPTS;
        for (int j = s0; j < s1; j++) vsorted[j] = v;
        if ((s0 >> 4) != ((s1 - 1) >> 4)) {   // spans a window boundary
            float4 z4 = {0.f, 0.f, 0.f, 0.f};
            float4* pv = (float4*)&v0[(long)v * 64];
            float4* py = (float4*)&y1m[(long)v * 64];
#pragma unroll
            for (int u = 0; u < 16; u++) { pv[u] = z4; py[u] = z4; }
        }
    }
    if (v == 0) vstart[NVOX] = NPTS;
}

// ---- K2: Gram stats (in-register, fully unrolled) + counting-sort scatter
// of ONE packed 16B record {feat, v, i} per point (halves scatter lines vs
// two 4B arrays; removes the ord/feat gathers downstream). ----
__global__ __launch_bounds__(256, 4)
void k_prep(const __hip_bfloat16* __restrict__ feat,
            const int* __restrict__ inv,
            const int* __restrict__ coors,
            const float* __restrict__ acc4,
            int* __restrict__ voff,
            uint4* __restrict__ pfs,
            float* __restrict__ gram) {
    __shared__ float gs[72];
    int t = threadIdx.x;
    if (t < 72) gs[t] = 0.0f;
    __syncthreads();

    float sx[10], sxx[55];
#pragma unroll
    for (int a = 0; a < 10; a++) sx[a] = 0.0f;
#pragma unroll
    for (int a = 0; a < 55; a++) sxx[a] = 0.0f;

    for (long i = (long)blockIdx.x * 256 + t; i < NPTS; i += (long)GBLK * 256) {
        int v = inv[i];
        uint2 f2 = *(const uint2*)(feat + 4 * i);   // 4 bf16
        float xv[10];
        compute_x_from(f2.x, f2.y, acc4, coors, v, xv);
        int idx = 0;
#pragma unroll
        for (int a = 0; a < 10; a++) {
            sx[a] += xv[a];
#pragma unroll
            for (int b = 0; b <= a; b++) sxx[idx++] += xv[a] * xv[b];
        }
        int pos = atomicAdd(&voff[v], 1);
        uint4 rec = { f2.x, f2.y, (unsigned int)v, (unsigned int)i };
        pfs[pos] = rec;
    }

#pragma unroll
    for (int v = 0; v < 65; v++) {
        float s = (v < 10) ? sx[v] : sxx[v - 10];
        for (int m = 32; m >= 1; m >>= 1) s += __shfl_xor(s, m);
        if ((t & 63) == 0) atomicAdd(&gs[v], s);
    }
    __syncthreads();
    if (t < 65) atomicAdd(&gram[t], gs[t]);
}

// ---- K3: h0 = relu(bn0(y0)); sorted tile read straight from pfs (coalesced,
// no ord/feat gathers; acc4/coors gathers are near-coalesced since v is
// sorted). Wave 1 folds the BN0 finalize from the Gram into LDS. Window-
// complete voxels get PLAIN stores; spanning voxels use atomicMax. Spills
// the h0 tile (bf16, sorted layout) for layer 1. ----
__global__ __launch_bounds__(256, 6)
void k_h0max(const uint4* __restrict__ pfs,
             const int* __restrict__ vstart,
             const float* __restrict__ acc4, const int* __restrict__ coors,
             const float* __restrict__ W0f, const float* __restrict__ gram,
             const __hip_bfloat16* __restrict__ g0,
             const __hip_bfloat16* __restrict__ be0,
             float* __restrict__ v0, unsigned short* __restrict__ h0t) {
    __shared__ float ht[64 * HT_LD];      // 16640 B
    __shared__ int invs[64];
    __shared__ float sc0s[64], bi0s[64];  // total ~17.4 KB
    int t = threadIdx.x, w = t >> 6, l = t & 63;
    int base = blockIdx.x * 64;
    uint4 rec = pfs[base + l];
    int v = (int)rec.z;
    if (w == 0) invs[l] = v;

    float xv[10];
    compute_x_from(rec.x, rec.y, acc4, coors, v, xv);

    if (w == 1) {
        // BN0 finalize from Gram (per-block redundant, ~100 FMA — trivial)
        int c = l;
        float wr[10];
#pragma unroll
        for (int k = 0; k < 10; k++) wr[k] = W0f[c * 10 + k];
        float sum = 0.0f, sq = 0.0f;
#pragma unroll
        for (int a = 0; a < 10; a++) {
            sum += wr[a] * gram[a];
            float ta = 0.0f;
#pragma unroll
            for (int b = 0; b < 10; b++) {
                int hi = (a >= b) ? a : b, lo = (a >= b) ? b : a;
                ta += wr[b] * gram[10 + hi * (hi + 1) / 2 + lo];
            }
            sq += wr[a] * ta;
        }
        float mu  = sum * (1.0f / NPTS);
        float var = sq * (1.0f / NPTS) - mu * mu;
        float g   = b2f(g0[c]) * rsqrtf(var + EPSB);
        sc0s[c] = g;
        bi0s[c] = b2f(be0[c]) - mu * g;
    }
    __syncthreads();

    int cw = w * 16;
#pragma unroll
    for (int j = 0; j < 16; j++) {
        int c = cw + j;
        float y = 0.0f;
#pragma unroll
        for (int k = 0; k < 10; k++) y += xv[k] * W0f[c*10 + k];
        ht[l * HT_LD + c] = fmaxf(sc0s[c] * y + bi0s[c], 0.0f);
    }
    __syncthreads();

    // spill h0 tile (bf16, sorted layout) — issued first so the global
    // stores drain underneath the max-walk below
#pragma unroll
    for (int u = 0; u < 2; u++) {
        int idx = t + u * 256;          // 0..511, coalesced uint4 per thread
        int pt2 = idx >> 3;
        int c0 = (idx & 7) * 8;
        const float* src = &ht[pt2 * HT_LD + c0];
        float4 a  = *(const float4*)src;
        float4 b4 = *(const float4*)(src + 4);
        uint4 o;
        o.x = (unsigned int)bf16u(a.x)  | ((unsigned int)bf16u(a.y)  << 16);
        o.y = (unsigned int)bf16u(a.z)  | ((unsigned int)bf16u(a.w)  << 16);
        o.z = (unsigned int)bf16u(b4.x) | ((unsigned int)bf16u(b4.y) << 16);
        o.w = (unsigned int)bf16u(b4.z) | ((unsigned int)bf16u(b4.w) << 16);
        *(uint4*)&h0t[(long)(base + pt2) * 64 + c0] = o;
    }

    // lane = channel; wave walks its 16 sorted points; run-combine
    unsigned int mk = 0u;
#pragma unroll
    for (int j = 0; j < 16; j++) {
        int p = cw + j;
        unsigned int hb = __float_as_uint(ht[p * HT_LD + l]);
        mk = (hb > mk) ? hb : mk;
        if (j == 15 || invs[p + 1] != invs[p]) {
            int vv = invs[p];
            int s0 = vstart[vv], s1 = vstart[vv + 1];
            unsigned int* dst = (unsigned int*)&v0[(long)vv * 64 + l];
            if (s0 >= base + cw && s1 <= base + cw + 16)
                *dst = mk;                 // voxel complete in window: final value
            else
                atomicMax(dst, mk);        // spans window/tile boundary
            mk = 0u;
        }
    }
}

// ---- K4: layer-1 MFMA over sorted tiles. h0 half of x1 comes straight from
// the precomputed h0t tile (pure coalesced copy); v0 half is a row copy+cvt;
// raw-y1 segment max with the same plain-store/atomic split (fkey keys). ----
__global__ __launch_bounds__(256, 6)
void k_mfma_stats(const int* __restrict__ vsorted,
                  const int* __restrict__ vstart,
                  const unsigned short* __restrict__ h0t,
                  const unsigned short* __restrict__ w1b,
                  const float* __restrict__ v0,
                  float* __restrict__ P1,
                  unsigned int* __restrict__ y1m) {
    __shared__ union {
        unsigned short xtb[64 * XTB_LD];
        float ht[64 * HT_LD];
    } sm;
    __shared__ int invs[64];
    int t = threadIdx.x, w = t >> 6, l = t & 63;
    int quad = l >> 4, lm = l & 15;
    int base = blockIdx.x * 64;
    if (w == 0) invs[l] = vsorted[base + l];

    bf16x8 bfrag[4];
    const uint4* wf = (const uint4*)w1b;
#pragma unroll
    for (int ks = 0; ks < 4; ks++)
        bfrag[ks] = __builtin_bit_cast(bf16x8, wf[(w * 4 + ks) * 64 + l]);

    // ---- stage x1 tile (bf16 [pt][k]): h0 half is a coalesced tile copy ----
#pragma unroll
    for (int u = 0; u < 2; u++) {
        int idx = t + u * 256;
        int pt = idx >> 3, c0 = (idx & 7) * 8;
        uint4 d = *(const uint4*)&h0t[(long)(base + pt) * 64 + c0];
        *(uint4*)&sm.xtb[pt * XTB_LD + c0] = d;
    }
    {
        // v0 half: 4 lanes/pt copy the voxel's final h0 row, fp32 -> bf16
        int p = t >> 2, q = t & 3;
        int vv = vsorted[base + p];
        const float4* src = (const float4*)&v0[(long)vv * 64 + q * 16];
#pragma unroll
        for (int u = 0; u < 4; u++) {
            float4 f4 = src[u];
            ushort4 s4 = { bf16u(f4.x), bf16u(f4.y), bf16u(f4.z), bf16u(f4.w) };
            *(ushort4*)&sm.xtb[p * XTB_LD + 64 + q * 16 + 4 * u] = s4;
        }
    }
    __syncthreads();

    // ---- MFMA ----
    f32x4 acc[4];
#pragma unroll
    for (int pg = 0; pg < 4; pg++) acc[pg] = (f32x4){0.f, 0.f, 0.f, 0.f};
#pragma unroll
    for (int ks = 0; ks < 4; ks++) {
#pragma unroll
        for (int pg = 0; pg < 4; pg++) {
            const uint4* ap = (const uint4*)&sm.xtb[(pg * 16 + lm) * XTB_LD + ks * 32 + quad * 8];
            bf16x8 a = __builtin_bit_cast(bf16x8, *ap);
            acc[pg] = __builtin_amdgcn_mfma_f32_16x16x32_bf16(a, bfrag[ks], acc[pg], 0, 0, 0);
        }
    }

    // ---- stats from accumulators ----
    float ssum = 0.0f, ssq = 0.0f;
#pragma unroll
    for (int pg = 0; pg < 4; pg++) {
#pragma unroll
        for (int r = 0; r < 4; r++) {
            float y = acc[pg][r];
            ssum += y; ssq += y * y;
        }
    }
    __syncthreads();   // all xtb reads done -> safe to overwrite with ht

    // raw y1 -> LDS transpose (C layout: row = quad*4+r, col = lm)
#pragma unroll
    for (int pg = 0; pg < 4; pg++) {
#pragma unroll
        for (int r = 0; r < 4; r++)
            sm.ht[(pg * 16 + quad * 4 + r) * HT_LD + w * 16 + lm] = acc[pg][r];
    }
    __syncthreads();

    // lane = channel; wave walks its 16 sorted points; plain-store/atomic split
    unsigned int mk = 0u;
    int cw = w * 16;
#pragma unroll
    for (int j = 0; j < 16; j++) {
        int p = cw + j;
        unsigned int k2 = fkey(sm.ht[p * HT_LD + l]);
        mk = (k2 > mk) ? k2 : mk;
        if (j == 15 || invs[p + 1] != invs[p]) {
            int vv = invs[p];
            int s0 = vstart[vv], s1 = vstart[vv + 1];
            unsigned int* dst = &y1m[(long)vv * 64 + l];
            if (s0 >= base + cw && s1 <= base + cw + 16)
                *dst = mk;
            else
                atomicMax(dst, mk);
            mk = 0u;
        }
    }

    ssum += __shfl_xor(ssum, 16); ssq += __shfl_xor(ssq, 16);
    ssum += __shfl_xor(ssum, 32); ssq += __shfl_xor(ssq, 32);
    if (l < 16) {
        int slot = blockIdx.x & 31;
        atomicAdd(&P1[slot * 128 + w * 16 + lm], ssum);
        atomicAdd(&P1[slot * 128 + 64 + w * 16 + lm], ssq);
    }
}

// ---- K5: emit output with INLINE BN1 finalize (per-block redundant P1 reduce).
// feats = relu(bn1(decode(y1max))); coors bf16-rounded. Grid-stride, 512 blocks.
#define OUTBLK 512
__global__ __launch_bounds__(256)
void k_out(const unsigned int* __restrict__ y1m,
           const float* __restrict__ P1,
           const __hip_bfloat16* __restrict__ gamma,
           const __hip_bfloat16* __restrict__ beta,
           const int* __restrict__ coors,
           float* __restrict__ out) {
    __shared__ float sc1s[64], bi1s[64];
    int t = threadIdx.x;
    if (t < 64) {
        float sum = 0.0f, sq = 0.0f;
        for (int s = 0; s < 32; s++) {
            sum += P1[s*128 + t];
            sq  += P1[s*128 + 64 + t];
        }
        float mu  = sum * (1.0f / NPTS);
        float var = sq * (1.0f / NPTS) - mu * mu;
        float g   = b2f(gamma[t]) * rsqrtf(var + EPSB);
        sc1s[t] = g;
        bi1s[t] = b2f(beta[t]) - mu * g;
    }
    __syncthreads();

    const long n4feat = (long)NVOX * 16;   // uint4 chunks of y1m
    const long n4all  = n4feat + NVOX;     // + int4 chunks of coors
    const long nfeat  = (long)NVOX * 64;
    for (long idx = (long)blockIdx.x * 256 + t; idx < n4all; idx += (long)OUTBLK * 256) {
        if (idx < n4feat) {
            uint4 kk = ((const uint4*)y1m)[idx];
            int c0 = (int)((idx * 4) & 63);
            float4 o;
            o.x = fmaxf(sc1s[c0+0] * funkey(kk.x) + bi1s[c0+0], 0.0f);
            o.y = fmaxf(sc1s[c0+1] * funkey(kk.y) + bi1s[c0+1], 0.0f);
            o.z = fmaxf(sc1s[c0+2] * funkey(kk.z) + bi1s[c0+2], 0.0f);
            o.w = fmaxf(sc1s[c0+3] * funkey(kk.w) + bi1s[c0+3], 0.0f);
            ((float4*)out)[idx] = o;
        } else {
            long vi = idx - n4feat;
            int4 c4 = ((const int4*)coors)[vi];
            float4 o;
            o.x = b2f(__float2bfloat16((float)c4.x));
            o.y = b2f(__float2bfloat16((float)c4.y));
            o.z = b2f(__float2bfloat16((float)c4.z));
            o.w = b2f(__float2bfloat16((float)c4.w));
            ((float4*)(out + nfeat))[vi] = o;
        }
    }
}

extern "C" void kernel_launch(void* const* d_in, const int* in_sizes, int n_in,
                              void* d_out, int out_size, void* d_ws, size_t ws_size,
                              hipStream_t stream) {
    const __hip_bfloat16* feat = (const __hip_bfloat16*)d_in[0];
    const __hip_bfloat16* W0   = (const __hip_bfloat16*)d_in[1];
    const __hip_bfloat16* g0   = (const __hip_bfloat16*)d_in[2];
    const __hip_bfloat16* be0  = (const __hip_bfloat16*)d_in[3];
    const __hip_bfloat16* W1   = (const __hip_bfloat16*)d_in[4];
    const __hip_bfloat16* g1   = (const __hip_bfloat16*)d_in[5];
    const __hip_bfloat16* be1  = (const __hip_bfloat16*)d_in[6];
    const int* inv   = (const int*)d_in[7];
    const int* coors = (const int*)d_in[8];
    float* out = (float*)d_out;

    float* ws    = (float*)d_ws;
    float* acc4  = ws + OFF_ACC4;
    float* gram  = ws + OFF_GRAM;
    float* P1    = ws + OFF_P1;
    float* v0    = ws + OFF_V0;
    unsigned int* y1m = (unsigned int*)(ws + OFF_Y1M);
    int* vtmp    = (int*)(ws + OFF_VTMP);
    int* bsum    = (int*)(ws + OFF_BSUM);
    int* voff    = (int*)(ws + OFF_VOFF);
    int* vstart  = (int*)(ws + OFF_VSTART);
    int* vsorted = (int*)(ws + OFF_VS);
    float* W0f   = ws + OFF_W0F;
    unsigned short* w1b = (unsigned short*)(ws + OFF_W1B);
    uint4* pfs   = (uint4*)(ws + OFF_PFS);
    unsigned short* h0t = (unsigned short*)(ws + OFF_H0T);

    // Only atomic-accumulated buffers need zeroing (acc4, gram, P1);
    // v0/y1m spanning rows are zeroed selectively by k_scan3.
    hipMemsetAsync(ws, 0, (size_t)ZERO_FLOATS * sizeof(float), stream);

    k_vsum<<<6251, 256, 0, stream>>>(feat, inv, acc4, W0, W1, W0f, w1b);
    k_scan1<<<NBLK_SCAN, 256, 0, stream>>>(acc4, vtmp, bsum);
    k_scan2<<<1, 512, 0, stream>>>(bsum);
    k_scan3<<<NBLK_SCAN, 256, 0, stream>>>(vtmp, bsum, voff, vstart, vsorted, v0, y1m);
    k_prep<<<GBLK, 256, 0, stream>>>(feat, inv, coors, acc4, voff, pfs, gram);
    k_h0max<<<NTILE, 256, 0, stream>>>(pfs, vstart, acc4, coors,
                                       W0f, gram, g0, be0, v0, h0t);
    k_mfma_stats<<<NTILE, 256, 0, stream>>>(vsorted, vstart, h0t, w1b, v0, P1, y1m);
    k_out<<<OUTBLK, 256, 0, stream>>>(y1m, P1, g1, be1, coors, out);
}

// Round 7
// 256.878 us; speedup vs baseline: 1.1084x; 1.1084x over previous
//
#include <hip/hip_runtime.h>
#include <hip/hip_bf16.h>

// Problem constants (match reference)
#define NPTS 400000          // == 6250 * 64 exactly
#define NVOX 100000
#define EPSB 1e-3f
#define NTILE 6250
#define NBLK_SCAN 391        // ceil(NVOX/256)
#define GBLK 782             // k_prep grid (2-3 pts/thread)

// ws layout (in floats) — ~108 MB
#define OFF_ACC4   0                          // 4*NVOX [cnt,sx,sy,sz]
#define OFF_GRAM   (4*NVOX)                   // 72: sx[10]+sxx[55]
#define OFF_P1     (OFF_GRAM + 128)           // 32 slots * 128
#define ZERO_FLOATS (OFF_P1 + 4096)           // zeroed prefix (~1.6 MB)
#define OFF_V0     ZERO_FLOATS                // NVOX*64 fp32 h0 max (spanning rows zeroed by scan3)
#define OFF_Y1M    (OFF_V0 + NVOX*64)         // NVOX*64 raw y1 max (fkey; spanning rows zeroed)
#define OFF_VTMP   (OFF_Y1M + NVOX*64)        // NVOX
#define OFF_BSUM   (OFF_VTMP + NVOX)          // 512
#define OFF_VOFF   (OFF_BSUM + 512)           // NVOX (scatter cursors)
#define OFF_VSTART (OFF_VOFF + NVOX)          // NVOX+8 (+ sentinel)
#define OFF_ORD    (OFF_VSTART + NVOX + 8)    // NPTS
#define OFF_VS     (OFF_ORD + NPTS)           // NPTS (vsorted, sequential fill by scan3)
#define OFF_W0F    (OFF_VS + NPTS)            // 640
#define OFF_W1B    (OFF_W0F + 640)            // 4096 floats = 8192 bf16
#define OFF_H0T    (OFF_W1B + 4096)           // NPTS*64 bf16 = NPTS*32 floats (sorted h0 tiles)

#define XTB_LD 136
#define HT_LD  65

typedef __bf16 bf16x8 __attribute__((ext_vector_type(8)));
typedef float  f32x4  __attribute__((ext_vector_type(4)));

__device__ __forceinline__ float b2f(__hip_bfloat16 h) { return __bfloat162float(h); }
__device__ __forceinline__ float bfbits2f(unsigned short u) {
    return __uint_as_float((unsigned int)u << 16);
}
__device__ __forceinline__ unsigned short bf16u(float f) {
    __hip_bfloat16 h = __float2bfloat16(f);
    return __builtin_bit_cast(unsigned short, h);
}
__device__ __forceinline__ unsigned int fkey(float f) {
    unsigned int u = __float_as_uint(f);
    return (u & 0x80000000u) ? ~u : (u | 0x80000000u);
}
__device__ __forceinline__ float funkey(unsigned int k) {
    unsigned int u = (k & 0x80000000u) ? (k & 0x7FFFFFFFu) : ~k;
    return __uint_as_float(u);
}

__device__ __forceinline__ void compute_x(const __hip_bfloat16* __restrict__ feat,
                                          const float* __restrict__ acc4,
                                          const int* __restrict__ coors,
                                          long i, int v, float* xv) {
    ushort4 f4 = *(const ushort4*)(feat + 4 * i);
    float px = bfbits2f(f4.x), py = bfbits2f(f4.y), pz = bfbits2f(f4.z), it = bfbits2f(f4.w);
    float4 a4 = *(const float4*)&acc4[4 * (long)v];
    float ic = 1.0f / a4.x;
    int4 c4 = *(const int4*)&coors[4 * (long)v];   // (b, z, y, x)
    xv[0] = px; xv[1] = py; xv[2] = pz;
    xv[3] = px - a4.y * ic; xv[4] = py - a4.z * ic; xv[5] = pz - a4.w * ic;
    xv[6] = px - ((float)c4.w * 0.2f + 0.1f);
    xv[7] = py - ((float)c4.z * 0.2f + 0.1f - 40.0f);
    xv[8] = pz - ((float)c4.y * 4.0f + 2.0f - 3.0f);
    xv[9] = it;
}

// ---- K1: per-voxel count + xyz sums; last block converts weights
// (W0 -> fp32; W1 -> bf16 MFMA B-fragment order). ----
__global__ void k_vsum(const __hip_bfloat16* __restrict__ feat,
                       const int* __restrict__ inv,
                       float* __restrict__ acc4,
                       const __hip_bfloat16* __restrict__ W0,
                       const __hip_bfloat16* __restrict__ W1,
                       float* __restrict__ W0f, unsigned short* __restrict__ w1b) {
    if (blockIdx.x == 6250) {
        int t = threadIdx.x;
        for (int j = t; j < 640; j += 256) W0f[j] = b2f(W0[j]);
        for (int f = t; f < 8192; f += 256) {
            int j  = f & 7;
            int l  = (f >> 3) & 63;
            int ks = (f >> 9) & 3;
            int ct = f >> 11;
            int ch = ct * 16 + (l & 15);
            int k  = ks * 32 + ((l >> 4) & 3) * 8 + j;
            w1b[f] = __builtin_bit_cast(unsigned short, W1[ch * 128 + k]);
        }
        return;
    }
    long t = (long)blockIdx.x * 256 + threadIdx.x;
    int pt = (int)(t >> 2);
    int comp = (int)(t & 3);
    float val = (comp == 0) ? 1.0f : b2f(feat[4 * pt + comp - 1]);
    int v = inv[pt];
    atomicAdd(&acc4[(long)v * 4 + comp], val);
}

// ---- prefix scan of voxel counts ----
__global__ void k_scan1(const float* __restrict__ acc4,
                        int* __restrict__ vtmp, int* __restrict__ bsum) {
    __shared__ int sc[256];
    int b = blockIdx.x, t = threadIdx.x;
    int v = b * 256 + t;
    int c = (v < NVOX) ? (int)acc4[4 * (long)v] : 0;
    sc[t] = c;
    __syncthreads();
    int val = c;
    for (int off = 1; off < 256; off <<= 1) {
        int x = (t >= off) ? sc[t - off] : 0;
        __syncthreads();
        val += x; sc[t] = val;
        __syncthreads();
    }
    if (v < NVOX) vtmp[v] = val - c;
    if (t == 255) bsum[b] = val;
}

__global__ void k_scan2(int* __restrict__ bsum) {
    __shared__ int sc[512];
    int t = threadIdx.x;
    int c = (t < NBLK_SCAN) ? bsum[t] : 0;
    sc[t] = c;
    __syncthreads();
    int val = c;
    for (int off = 1; off < 512; off <<= 1) {
        int x = (t >= off) ? sc[t - off] : 0;
        __syncthreads();
        val += x; sc[t] = val;
        __syncthreads();
    }
    if (t < NBLK_SCAN) bsum[t] = val - c;
}

// ---- scan3: finalize offsets; fill vsorted by sequential per-voxel runs
// (streaming writes — removes the vsorted scatter from k_prep); zero-init
// v0/y1m rows ONLY for voxels that span an aligned 16-pt window. ----
__global__ void k_scan3(const int* __restrict__ vtmp, const int* __restrict__ bsum,
                        int* __restrict__ voff, int* __restrict__ vstart,
                        int* __restrict__ vsorted,
                        float* __restrict__ v0, unsigned int* __restrict__ y1m) {
    int v = blockIdx.x * 256 + threadIdx.x;
    if (v < NVOX) {
        int s0 = vtmp[v] + bsum[v >> 8];
        voff[v] = s0;
        vstart[v] = s0;
        int s1;
        if (v + 1 < NVOX) s1 = vtmp[v + 1] + bsum[(v + 1) >> 8];
        else              s1 = NPTS;
        for (int j = s0; j < s1; j++) vsorted[j] = v;
        if ((s0 >> 4) != ((s1 - 1) >> 4)) {   // spans a window boundary
            float4 z4 = {0.f, 0.f, 0.f, 0.f};
            float4* pv = (float4*)&v0[(long)v * 64];
            float4* py = (float4*)&y1m[(long)v * 64];
#pragma unroll
            for (int u = 0; u < 16; u++) { pv[u] = z4; py[u] = z4; }
        }
    }
    if (v == 0) vstart[NVOX] = NPTS;
}

// ---- K2: Gram stats (in-register, fully unrolled) + counting-sort scatter
// of ONLY the point index (4B/pt — vsorted comes from scan3's streaming
// fill, halving random scatter line-touches vs round-5). ----
__global__ __launch_bounds__(256, 4)
void k_prep(const __hip_bfloat16* __restrict__ feat,
            const int* __restrict__ inv,
            const int* __restrict__ coors,
            const float* __restrict__ acc4,
            int* __restrict__ voff,
            int* __restrict__ ord,
            float* __restrict__ gram) {
    __shared__ float gs[72];
    int t = threadIdx.x;
    if (t < 72) gs[t] = 0.0f;
    __syncthreads();

    float sx[10], sxx[55];
#pragma unroll
    for (int a = 0; a < 10; a++) sx[a] = 0.0f;
#pragma unroll
    for (int a = 0; a < 55; a++) sxx[a] = 0.0f;

    for (long i = (long)blockIdx.x * 256 + t; i < NPTS; i += (long)GBLK * 256) {
        int v = inv[i];
        float xv[10];
        compute_x(feat, acc4, coors, i, v, xv);
        int idx = 0;
#pragma unroll
        for (int a = 0; a < 10; a++) {
            sx[a] += xv[a];
#pragma unroll
            for (int b = 0; b <= a; b++) sxx[idx++] += xv[a] * xv[b];
        }
        int pos = atomicAdd(&voff[v], 1);
        ord[pos] = (int)i;
    }

#pragma unroll
    for (int v = 0; v < 65; v++) {
        float s = (v < 10) ? sx[v] : sxx[v - 10];
        for (int m = 32; m >= 1; m >>= 1) s += __shfl_xor(s, m);
        if ((t & 63) == 0) atomicAdd(&gs[v], s);
    }
    __syncthreads();
    if (t < 65) atomicAdd(&gram[t], gs[t]);
}

// ---- K3: h0 = relu(bn0(y0)); sorted tile; wave 1 folds the BN0 finalize
// (from the Gram matrix) into LDS while other waves' gathers are in flight.
// Window-complete voxels get PLAIN coalesced stores; only window-spanning
// voxels use atomicMax. Spills the h0 tile to global (bf16, sorted layout)
// — the layer-1 A operand — so k_mfma_stats never recomputes layer 0. ----
__global__ __launch_bounds__(256, 6)
void k_h0max(const int* __restrict__ ord, const int* __restrict__ vsorted,
             const int* __restrict__ vstart,
             const __hip_bfloat16* __restrict__ feat,
             const float* __restrict__ acc4, const int* __restrict__ coors,
             const float* __restrict__ W0f, const float* __restrict__ gram,
             const __hip_bfloat16* __restrict__ g0,
             const __hip_bfloat16* __restrict__ be0,
             float* __restrict__ v0, unsigned short* __restrict__ h0t) {
    __shared__ float ht[64 * HT_LD];      // 16640 B
    __shared__ int invs[64];
    __shared__ float sc0s[64], bi0s[64];  // total ~17.4 KB
    int t = threadIdx.x, w = t >> 6, l = t & 63;
    int base = blockIdx.x * 64;
    int i = ord[base + l];
    int v = vsorted[base + l];
    if (w == 0) invs[l] = v;

    float xv[10];
    compute_x(feat, acc4, coors, (long)i, v, xv);

    if (w == 1) {
        // BN0 finalize from Gram (per-block redundant, ~100 FMA — trivial)
        int c = l;
        float wr[10];
#pragma unroll
        for (int k = 0; k < 10; k++) wr[k] = W0f[c * 10 + k];
        float sum = 0.0f, sq = 0.0f;
#pragma unroll
        for (int a = 0; a < 10; a++) {
            sum += wr[a] * gram[a];
            float ta = 0.0f;
#pragma unroll
            for (int b = 0; b < 10; b++) {
                int hi = (a >= b) ? a : b, lo = (a >= b) ? b : a;
                ta += wr[b] * gram[10 + hi * (hi + 1) / 2 + lo];
            }
            sq += wr[a] * ta;
        }
        float mu  = sum * (1.0f / NPTS);
        float var = sq * (1.0f / NPTS) - mu * mu;
        float g   = b2f(g0[c]) * rsqrtf(var + EPSB);
        sc0s[c] = g;
        bi0s[c] = b2f(be0[c]) - mu * g;
    }
    __syncthreads();

    int cw = w * 16;
#pragma unroll
    for (int j = 0; j < 16; j++) {
        int c = cw + j;
        float y = 0.0f;
#pragma unroll
        for (int k = 0; k < 10; k++) y += xv[k] * W0f[c*10 + k];
        ht[l * HT_LD + c] = fmaxf(sc0s[c] * y + bi0s[c], 0.0f);
    }
    __syncthreads();

    // spill h0 tile (bf16, sorted layout) — issued first so the global
    // stores drain underneath the max-walk below
#pragma unroll
    for (int u = 0; u < 2; u++) {
        int idx = t + u * 256;          // 0..511, coalesced uint4 per thread
        int pt2 = idx >> 3;
        int c0 = (idx & 7) * 8;
        const float* src = &ht[pt2 * HT_LD + c0];
        float4 a  = *(const float4*)src;
        float4 b4 = *(const float4*)(src + 4);
        uint4 o;
        o.x = (unsigned int)bf16u(a.x)  | ((unsigned int)bf16u(a.y)  << 16);
        o.y = (unsigned int)bf16u(a.z)  | ((unsigned int)bf16u(a.w)  << 16);
        o.z = (unsigned int)bf16u(b4.x) | ((unsigned int)bf16u(b4.y) << 16);
        o.w = (unsigned int)bf16u(b4.z) | ((unsigned int)bf16u(b4.w) << 16);
        *(uint4*)&h0t[(long)(base + pt2) * 64 + c0] = o;
    }

    // lane = channel; wave walks its 16 sorted points; run-combine
    unsigned int mk = 0u;
#pragma unroll
    for (int j = 0; j < 16; j++) {
        int p = cw + j;
        unsigned int hb = __float_as_uint(ht[p * HT_LD + l]);
        mk = (hb > mk) ? hb : mk;
        if (j == 15 || invs[p + 1] != invs[p]) {
            int vv = invs[p];
            int s0 = vstart[vv], s1 = vstart[vv + 1];
            unsigned int* dst = (unsigned int*)&v0[(long)vv * 64 + l];
            if (s0 >= base + cw && s1 <= base + cw + 16)
                *dst = mk;                 // voxel complete in window: final value
            else
                atomicMax(dst, mk);        // spans window/tile boundary
            mk = 0u;
        }
    }
}

// ---- K4: layer-1 MFMA over sorted tiles. h0 half of x1 comes straight from
// the precomputed h0t tile (pure coalesced copy); v0 half is a row copy+cvt;
// raw-y1 segment max with the same plain-store/atomic split (fkey keys). ----
__global__ __launch_bounds__(256, 6)
void k_mfma_stats(const int* __restrict__ vsorted,
                  const int* __restrict__ vstart,
                  const unsigned short* __restrict__ h0t,
                  const unsigned short* __restrict__ w1b,
                  const float* __restrict__ v0,
                  float* __restrict__ P1,
                  unsigned int* __restrict__ y1m) {
    __shared__ union {
        unsigned short xtb[64 * XTB_LD];
        float ht[64 * HT_LD];
    } sm;
    __shared__ int invs[64];
    int t = threadIdx.x, w = t >> 6, l = t & 63;
    int quad = l >> 4, lm = l & 15;
    int base = blockIdx.x * 64;
    if (w == 0) invs[l] = vsorted[base + l];

    bf16x8 bfrag[4];
    const uint4* wf = (const uint4*)w1b;
#pragma unroll
    for (int ks = 0; ks < 4; ks++)
        bfrag[ks] = __builtin_bit_cast(bf16x8, wf[(w * 4 + ks) * 64 + l]);

    // ---- stage x1 tile (bf16 [pt][k]): h0 half is a coalesced tile copy ----
#pragma unroll
    for (int u = 0; u < 2; u++) {
        int idx = t + u * 256;
        int pt = idx >> 3, c0 = (idx & 7) * 8;
        uint4 d = *(const uint4*)&h0t[(long)(base + pt) * 64 + c0];
        *(uint4*)&sm.xtb[pt * XTB_LD + c0] = d;
    }
    {
        // v0 half: 4 lanes/pt copy the voxel's final h0 row, fp32 -> bf16
        int p = t >> 2, q = t & 3;
        int vv = vsorted[base + p];
        const float4* src = (const float4*)&v0[(long)vv * 64 + q * 16];
#pragma unroll
        for (int u = 0; u < 4; u++) {
            float4 f4 = src[u];
            ushort4 s4 = { bf16u(f4.x), bf16u(f4.y), bf16u(f4.z), bf16u(f4.w) };
            *(ushort4*)&sm.xtb[p * XTB_LD + 64 + q * 16 + 4 * u] = s4;
        }
    }
    __syncthreads();

    // ---- MFMA ----
    f32x4 acc[4];
#pragma unroll
    for (int pg = 0; pg < 4; pg++) acc[pg] = (f32x4){0.f, 0.f, 0.f, 0.f};
#pragma unroll
    for (int ks = 0; ks < 4; ks++) {
#pragma unroll
        for (int pg = 0; pg < 4; pg++) {
            const uint4* ap = (const uint4*)&sm.xtb[(pg * 16 + lm) * XTB_LD + ks * 32 + quad * 8];
            bf16x8 a = __builtin_bit_cast(bf16x8, *ap);
            acc[pg] = __builtin_amdgcn_mfma_f32_16x16x32_bf16(a, bfrag[ks], acc[pg], 0, 0, 0);
        }
    }

    // ---- stats from accumulators ----
    float ssum = 0.0f, ssq = 0.0f;
#pragma unroll
    for (int pg = 0; pg < 4; pg++) {
#pragma unroll
        for (int r = 0; r < 4; r++) {
            float y = acc[pg][r];
            ssum += y; ssq += y * y;
        }
    }
    __syncthreads();   // all xtb reads done -> safe to overwrite with ht

    // raw y1 -> LDS transpose (C layout: row = quad*4+r, col = lm)
#pragma unroll
    for (int pg = 0; pg < 4; pg++) {
#pragma unroll
        for (int r = 0; r < 4; r++)
            sm.ht[(pg * 16 + quad * 4 + r) * HT_LD + w * 16 + lm] = acc[pg][r];
    }
    __syncthreads();

    // lane = channel; wave walks its 16 sorted points; plain-store/atomic split
    unsigned int mk = 0u;
    int cw = w * 16;
#pragma unroll
    for (int j = 0; j < 16; j++) {
        int p = cw + j;
        unsigned int k2 = fkey(sm.ht[p * HT_LD + l]);
        mk = (k2 > mk) ? k2 : mk;
        if (j == 15 || invs[p + 1] != invs[p]) {
            int vv = invs[p];
            int s0 = vstart[vv], s1 = vstart[vv + 1];
            unsigned int* dst = &y1m[(long)vv * 64 + l];
            if (s0 >= base + cw && s1 <= base + cw + 16)
                *dst = mk;
            else
                atomicMax(dst, mk);
            mk = 0u;
        }
    }

    ssum += __shfl_xor(ssum, 16); ssq += __shfl_xor(ssq, 16);
    ssum += __shfl_xor(ssum, 32); ssq += __shfl_xor(ssq, 32);
    if (l < 16) {
        int slot = blockIdx.x & 31;
        atomicAdd(&P1[slot * 128 + w * 16 + lm], ssum);
        atomicAdd(&P1[slot * 128 + 64 + w * 16 + lm], ssq);
    }
}

// ---- K5: emit output with INLINE BN1 finalize (per-block redundant P1 reduce).
// feats = relu(bn1(decode(y1max))); coors bf16-rounded. Grid-stride, 512 blocks.
#define OUTBLK 512
__global__ __launch_bounds__(256)
void k_out(const unsigned int* __restrict__ y1m,
           const float* __restrict__ P1,
           const __hip_bfloat16* __restrict__ gamma,
           const __hip_bfloat16* __restrict__ beta,
           const int* __restrict__ coors,
           float* __restrict__ out) {
    __shared__ float sc1s[64], bi1s[64];
    int t = threadIdx.x;
    if (t < 64) {
        float sum = 0.0f, sq = 0.0f;
        for (int s = 0; s < 32; s++) {
            sum += P1[s*128 + t];
            sq  += P1[s*128 + 64 + t];
        }
        float mu  = sum * (1.0f / NPTS);
        float var = sq * (1.0f / NPTS) - mu * mu;
        float g   = b2f(gamma[t]) * rsqrtf(var + EPSB);
        sc1s[t] = g;
        bi1s[t] = b2f(beta[t]) - mu * g;
    }
    __syncthreads();

    const long n4feat = (long)NVOX * 16;   // uint4 chunks of y1m
    const long n4all  = n4feat + NVOX;     // + int4 chunks of coors
    const long nfeat  = (long)NVOX * 64;
    for (long idx = (long)blockIdx.x * 256 + t; idx < n4all; idx += (long)OUTBLK * 256) {
        if (idx < n4feat) {
            uint4 kk = ((const uint4*)y1m)[idx];
            int c0 = (int)((idx * 4) & 63);
            float4 o;
            o.x = fmaxf(sc1s[c0+0] * funkey(kk.x) + bi1s[c0+0], 0.0f);
            o.y = fmaxf(sc1s[c0+1] * funkey(kk.y) + bi1s[c0+1], 0.0f);
            o.z = fmaxf(sc1s[c0+2] * funkey(kk.z) + bi1s[c0+2], 0.0f);
            o.w = fmaxf(sc1s[c0+3] * funkey(kk.w) + bi1s[c0+3], 0.0f);
            ((float4*)out)[idx] = o;
        } else {
            long vi = idx - n4feat;
            int4 c4 = ((const int4*)coors)[vi];
            float4 o;
            o.x = b2f(__float2bfloat16((float)c4.x));
            o.y = b2f(__float2bfloat16((float)c4.y));
            o.z = b2f(__float2bfloat16((float)c4.z));
            o.w = b2f(__float2bfloat16((float)c4.w));
            ((float4*)(out + nfeat))[vi] = o;
        }
    }
}

extern "C" void kernel_launch(void* const* d_in, const int* in_sizes, int n_in,
                              void* d_out, int out_size, void* d_ws, size_t ws_size,
                              hipStream_t stream) {
    const __hip_bfloat16* feat = (const __hip_bfloat16*)d_in[0];
    const __hip_bfloat16* W0   = (const __hip_bfloat16*)d_in[1];
    const __hip_bfloat16* g0   = (const __hip_bfloat16*)d_in[2];
    const __hip_bfloat16* be0  = (const __hip_bfloat16*)d_in[3];
    const __hip_bfloat16* W1   = (const __hip_bfloat16*)d_in[4];
    const __hip_bfloat16* g1   = (const __hip_bfloat16*)d_in[5];
    const __hip_bfloat16* be1  = (const __hip_bfloat16*)d_in[6];
    const int* inv   = (const int*)d_in[7];
    const int* coors = (const int*)d_in[8];
    float* out = (float*)d_out;

    float* ws    = (float*)d_ws;
    float* acc4  = ws + OFF_ACC4;
    float* gram  = ws + OFF_GRAM;
    float* P1    = ws + OFF_P1;
    float* v0    = ws + OFF_V0;
    unsigned int* y1m = (unsigned int*)(ws + OFF_Y1M);
    int* vtmp    = (int*)(ws + OFF_VTMP);
    int* bsum    = (int*)(ws + OFF_BSUM);
    int* voff    = (int*)(ws + OFF_VOFF);
    int* vstart  = (int*)(ws + OFF_VSTART);
    int* ord     = (int*)(ws + OFF_ORD);
    int* vsorted = (int*)(ws + OFF_VS);
    float* W0f   = ws + OFF_W0F;
    unsigned short* w1b = (unsigned short*)(ws + OFF_W1B);
    unsigned short* h0t = (unsigned short*)(ws + OFF_H0T);

    // Only atomic-accumulated buffers need zeroing (acc4, gram, P1);
    // v0/y1m spanning rows are zeroed selectively by k_scan3.
    hipMemsetAsync(ws, 0, (size_t)ZERO_FLOATS * sizeof(float), stream);

    k_vsum<<<6251, 256, 0, stream>>>(feat, inv, acc4, W0, W1, W0f, w1b);
    k_scan1<<<NBLK_SCAN, 256, 0, stream>>>(acc4, vtmp, bsum);
    k_scan2<<<1, 512, 0, stream>>>(bsum);
    k_scan3<<<NBLK_SCAN, 256, 0, stream>>>(vtmp, bsum, voff, vstart, vsorted, v0, y1m);
    k_prep<<<GBLK, 256, 0, stream>>>(feat, inv, coors, acc4, voff, ord, gram);
    k_h0max<<<NTILE, 256, 0, stream>>>(ord, vsorted, vstart, feat, acc4, coors,
                                       W0f, gram, g0, be0, v0, h0t);
    k_mfma_stats<<<NTILE, 256, 0, stream>>>(vsorted, vstart, h0t, w1b, v0, P1, y1m);
    k_out<<<OUTBLK, 256, 0, stream>>>(y1m, P1, g1, be1, coors, out);
}